// Round 5
// baseline (161.461 us; speedup 1.0000x reference)
//
#include <hip/hip_runtime.h>
#include <math.h>
#include <stdint.h>

#define NBATCH 16384
#define MB 16
#define NT 256
#define NBLOCKS (NBATCH/MB)
#define WT_BYTE_OFF 2560
#define XRP 488   // raw x LDS pitch (bf16 elems): 976B row, 244 dw % 32 = 20 -> 2-way
#define XQP 360   // permuted x LDS pitch: 720B row, 180 dw % 32 = 20 -> 2-way

typedef float  f32x4 __attribute__((ext_vector_type(4)));
typedef short  s16x8 __attribute__((ext_vector_type(8)));

// ---------------- path metadata (validated rounds 1-4) ----------------
__device__ const int P_CGOFF[15] = {0,1,10,35,44,53,80,125,170,245,270,315,390,415,490};
__device__ const int P_D2[15]    = {1,3,5,3,1,3,5,3,5,5,3,5,1,3,5};
__device__ const int P_D3[15]    = {1,1,1,3,3,3,3,3,3,5,5,5,5,5,5};
__device__ const int P_TSTART[15]= {0,1,4,9,12,21,30,39,54,69,74,89,104,129,154};
__device__ const int P_YOFF[15]  = {0,1,4,1,0,1,4,1,4,4,1,4,0,1,4};
__device__ const int CG_L1[15] = {0,1,2,0,1,1,1,2,2,0,1,1,2,2,2};
__device__ const int CG_L2[15] = {0,1,2,1,0,1,2,1,2,2,1,2,0,1,2};
__device__ const int CG_L3[15] = {0,0,0,1,1,1,1,1,1,2,2,2,2,2,2};

// ---------------- f32 CG math (factorials <=7! exact in f32; validated r4) ----------------
__device__ const float FCT[13] = {1.f,1.f,2.f,6.f,24.f,120.f,720.f,5040.f,40320.f,
                                  362880.f,3628800.f,39916800.f,479001600.f};

__device__ float su2f(int j1,int j2,int j3,int m1,int m2,int m3){
  float pref = sqrtf((float)(2*j3+1)*FCT[j1+j2-j3]*FCT[j1-j2+j3]*FCT[-j1+j2+j3]/FCT[j1+j2+j3+1]);
  pref *= sqrtf(FCT[j3+m3]*FCT[j3-m3]*FCT[j1-m1]*FCT[j1+m1]*FCT[j2-m2]*FCT[j2+m2]);
  float s = 0.f;
  for (int v=0; v<=j1+j2-j3; ++v){
    int a=j1+j2-j3-v, b=j1-m1-v, c=j2+m2-v, d=j3-j2+m1+v, e=j3-j1-m2+v;
    if (a<0||b<0||c<0||d<0||e<0) continue;
    float term = 1.f/(FCT[v]*FCT[a]*FCT[b]*FCT[c]*FCT[d]*FCT[e]);
    s += (v&1) ? -term : term;
  }
  return pref*s;
}

__device__ void qvalf(int l,int r,int c,float* qr,float* qi){
  int m = r - l;
  const float is2 = 0.70710678118654752440f;
  float br=0.f, bi=0.f;
  if (m<0){
    if (c == l - m) br = is2;
    else if (c == l + m) bi = -is2;
  } else if (m==0){
    if (c==l) br = 1.f;
  } else {
    float sg = (m&1)? -1.f : 1.f;
    if (c == l + m) br = sg*is2;
    else if (c == l - m) bi = sg*is2;
  }
  if (l==1){ float nr = bi, ni = -br; br=nr; bi=ni; }   // *(-i)
  else if (l==2){ br=-br; bi=-bi; }                     // *(-i)^2
  *qr=br; *qi=bi;
}

// ---------------- bf16 helpers ----------------
__device__ __forceinline__ uint32_t f2bf(float f){
  uint32_t u = __float_as_uint(f);
  return (u + 0x7fffu + ((u>>16)&1u)) >> 16;   // RNE
}
__device__ __forceinline__ float bf2f(uint32_t v){ return __uint_as_float(v << 16); }
__device__ __forceinline__ uint32_t pk2(float a, float b){ return (f2bf(b)<<16) | f2bf(a); }

// ---------------- prep: coalesced Wt pack + serial-f32 CG (no atomics/memset) ----------------
// ws layout: [0,2460) cg f32; [2560, 2560+129024) Wt bf16 [seg][v][u1]
__global__ void prep(const float* __restrict__ W0, const float* __restrict__ W1,
                     const float* __restrict__ W2, float* __restrict__ ws)
{
  const int t = blockIdx.x*NT + threadIdx.x;
  uint16_t* wt = (uint16_t*)((char*)ws + WT_BYTE_OFF);
  if (t < 28672){                       // g0: W0 is [224][128]; u=t>>7, v=t&127 -> W0[t]
    int u = t>>7, v = t&127, wb, mul, u1;
    if (u<128){wb=0; mul=128; u1=u;} else if (u<192){wb=16384; mul=64; u1=u-128;}
    else {wb=24576; mul=32; u1=u-192;}
    wt[wb + v*mul + u1] = (uint16_t)f2bf(W0[t]*0.066815310478f);
  } else if (t < 53248){                // g1: W1 [384][64]
    int t2 = t-28672, u = t2>>6, v = t2&63, wb, mul, u1;
    if (u<128){wb=28672; mul=128; u1=u;} else if (u<192){wb=36864; mul=64; u1=u-128;}
    else if (u<256){wb=40960; mul=64; u1=u-192;} else if (u<320){wb=45056; mul=64; u1=u-256;}
    else if (u<352){wb=49152; mul=32; u1=u-320;} else {wb=51200; mul=32; u1=u-352;}
    wt[wb + v*mul + u1] = (uint16_t)f2bf(W1[t2]*0.051031036308f);
  } else if (t < 64512){                // g2: W2 [352][32]
    int t3 = t-53248, u = t3>>5, v = t3&31, wb, mul, u1;
    if (u<128){wb=53248; mul=128; u1=u;} else if (u<192){wb=57344; mul=64; u1=u-128;}
    else if (u<256){wb=59392; mul=64; u1=u-192;} else if (u<288){wb=61440; mul=32; u1=u-256;}
    else if (u<320){wb=62464; mul=32; u1=u-288;} else {wb=63488; mul=32; u1=u-320;}
    wt[wb + v*mul + u1] = (uint16_t)f2bf(W2[t3]*0.053300179089f);
  } else if (t < 64512 + 615){          // CG entry, serial f32 (formula validated r1-r4)
    const int e = t - 64512;
    int p = 0;
    while (p < 14 && e >= P_CGOFF[p+1]) ++p;
    int r = e - P_CGOFF[p];
    int d2 = P_D2[p], d3 = P_D3[p];
    int i1 = r/(d2*d3); int rem = r - i1*(d2*d3);
    int i2 = rem/d3;    int i3 = rem - i2*d3;
    int l1 = CG_L1[p], l2 = CG_L2[p], l3 = CG_L3[p];
    float acc = 0.f;
    for (int i = 0; i <= 2*l1; ++i){
      for (int k = 0; k <= 2*l2; ++k){
        int n = i + k - l1 - l2 + l3;
        if (n < 0 || n > 2*l3) continue;
        float c = su2f(l1,l2,l3, i-l1, k-l2, n-l3);
        if (c == 0.f) continue;
        float q1r,q1i,q2r,q2i,q3r,q3i;
        qvalf(l1,i,i1,&q1r,&q1i);
        qvalf(l2,k,i2,&q2r,&q2i);
        qvalf(l3,n,i3,&q3r,&q3i);
        q3i = -q3i;                     // conj(Q3)
        float ar = q1r*q2r - q1i*q2i;
        float ai = q1r*q2i + q1i*q2r;
        acc += (ar*q3r - ai*q3i)*c;
      }
    }
    ws[e] = acc;
  }
}

// ---------------- per-group compile-time metadata ----------------
template<int G> struct GM;
template<> struct GM<0>{
  static constexpr int NS=3, D3=1, OB=0, NMT=2, NI3=1;
  static constexpr int MUL[3]={128,64,32};
  static constexpr int D1[3] ={1,3,5};
  static constexpr bool RAW[3]={true,false,false};
  static constexpr int PB[3] ={0,0,192};
  static constexpr int TS[3] ={0,1,4};
  static constexpr int WB[3] ={0,16384,24576};
};
template<> struct GM<1>{
  static constexpr int NS=6, D3=3, OB=128, NMT=1, NI3=3;
  static constexpr int MUL[6]={128,64,64,64,32,32};
  static constexpr int D1[6] ={1,3,3,3,5,5};
  static constexpr bool RAW[6]={true,false,false,false,false,false};
  static constexpr int PB[6] ={0,0,0,0,192,192};
  static constexpr int TS[6] ={9,12,21,30,39,54};
  static constexpr int WB[6] ={28672,36864,40960,45056,49152,51200};
};
template<> struct GM<2>{
  static constexpr int NS=6, D3=5, OB=320, NMT=1, NI3=3;
  static constexpr int MUL[6]={128,64,64,32,32,32};
  static constexpr int D1[6] ={1,3,3,5,5,5};
  static constexpr bool RAW[6]={true,false,false,false,false,false};
  static constexpr int PB[6] ={0,0,0,192,192,192};
  static constexpr int TS[6] ={69,74,89,104,129,154};
  static constexpr int WB[6] ={53248,57344,59392,61440,62464,63488};
};

// one segment: A=Wt(m=v), B=x(n=batch), K=mul; T-contract into acc (r4-verified)
template<int G, int S, int NMT, int NI3>
__device__ __forceinline__ void do_seg(const short* __restrict__ wt,
                                       const uint16_t* __restrict__ xr,
                                       const uint16_t* __restrict__ xq,
                                       const uint16_t* __restrict__ Tsh,
                                       f32x4 (&acc)[NMT][NI3],
                                       int ln, int koct, int mt0, int i3base, int ni3)
{
  using M = GM<G>;
  constexpr int MUL = M::MUL[S];
  constexpr int KS  = MUL >> 5;
  constexpr int D1  = M::D1[S];

  s16x8 Af[NMT][KS];
  #pragma unroll
  for (int mt = 0; mt < NMT; ++mt)
    #pragma unroll
    for (int kk = 0; kk < KS; ++kk)
      Af[mt][kk] = *(const s16x8*)(wt + M::WB[S] + ((mt0+mt)*16 + ln)*MUL + kk*32 + koct);

  const short* xbase = M::RAW[S] ? ((const short*)xr + ln*XRP)
                                 : ((const short*)xq + ln*XQP + M::PB[S]);
  #pragma unroll
  for (int i1 = 0; i1 < D1; ++i1){
    float tv[NI3];
    #pragma unroll
    for (int j = 0; j < NI3; ++j)
      if (j < ni3)
        tv[j] = bf2f(Tsh[(M::TS[S] + i1*M::D3 + i3base + j)*16 + ln]);
    s16x8 Bf[KS];
    #pragma unroll
    for (int kk = 0; kk < KS; ++kk)
      Bf[kk] = *(const s16x8*)(xbase + i1*MUL + kk*32 + koct);
    #pragma unroll
    for (int mt = 0; mt < NMT; ++mt){
      f32x4 D = {0.f,0.f,0.f,0.f};
      #pragma unroll
      for (int kk = 0; kk < KS; ++kk)
        D = __builtin_amdgcn_mfma_f32_16x16x32_bf16(Af[mt][kk], Bf[kk], D, 0, 0, 0);
      #pragma unroll
      for (int j = 0; j < NI3; ++j){
        if (j < ni3){
          acc[mt][j][0] += tv[j]*D[0];
          acc[mt][j][1] += tv[j]*D[1];
          acc[mt][j][2] += tv[j]*D[2];
          acc[mt][j][3] += tv[j]*D[3];
        }
      }
    }
  }
}

template<int G>
__device__ __forceinline__ void run_group(const short* __restrict__ wt,
                                          float* __restrict__ out, int b0, int tid,
                                          const uint16_t* __restrict__ Tsh,
                                          const uint16_t* __restrict__ xr,
                                          const uint16_t* __restrict__ xq)
{
  using M = GM<G>;
  const int lane = tid & 63, w = tid >> 6;
  const int ln   = lane & 15;          // A: m / B: n(batch) / D: col(batch)
  const int koct = (lane >> 4) * 8;
  constexpr int NMT = M::NMT, NI3 = M::NI3;

  int mt0, i3base, ni3;
  if constexpr (G == 0){ mt0 = 2*w; i3base = 0; ni3 = 1; }
  else if constexpr (G == 1){ mt0 = w; i3base = 0; ni3 = 3; }
  else { mt0 = w >> 1; i3base = (w & 1)*3; ni3 = (w & 1) ? 2 : 3; }

  f32x4 acc[NMT][NI3];
  #pragma unroll
  for (int a = 0; a < NMT; ++a)
    #pragma unroll
    for (int b = 0; b < NI3; ++b) acc[a][b] = (f32x4){0.f,0.f,0.f,0.f};

  do_seg<G,0,NMT,NI3>(wt, xr, xq, Tsh, acc, ln, koct, mt0, i3base, ni3);
  do_seg<G,1,NMT,NI3>(wt, xr, xq, Tsh, acc, ln, koct, mt0, i3base, ni3);
  do_seg<G,2,NMT,NI3>(wt, xr, xq, Tsh, acc, ln, koct, mt0, i3base, ni3);
  if constexpr (M::NS > 3){
    do_seg<G,(M::NS>3)?3:0,NMT,NI3>(wt, xr, xq, Tsh, acc, ln, koct, mt0, i3base, ni3);
    do_seg<G,(M::NS>4)?4:0,NMT,NI3>(wt, xr, xq, Tsh, acc, ln, koct, mt0, i3base, ni3);
    do_seg<G,(M::NS>5)?5:0,NMT,NI3>(wt, xr, xq, Tsh, acc, ln, koct, mt0, i3base, ni3);
  }

  // ---- stores: D col=lane&15=batch, rows=(lane>>4)*4+r = v (r3/r4-verified) ----
  const int rq = (lane >> 4) * 4;
  float* orow = out + (size_t)(b0 + ln)*480;
  if constexpr (G == 0){
    #pragma unroll
    for (int mt = 0; mt < NMT; ++mt){
      const int vb = (mt0+mt)*16 + rq;
      *(float4*)(orow + vb) = make_float4(acc[mt][0][0], acc[mt][0][1],
                                          acc[mt][0][2], acc[mt][0][3]);
    }
  } else if constexpr (G == 1){
    const int vb = mt0*16 + rq;
    float buf[12];
    #pragma unroll
    for (int r = 0; r < 4; ++r)
      #pragma unroll
      for (int j = 0; j < 3; ++j) buf[r*3+j] = acc[0][j][r];
    float* p = orow + 128 + vb*3;
    *(float4*)(p)   = make_float4(buf[0],buf[1],buf[2],buf[3]);
    *(float4*)(p+4) = make_float4(buf[4],buf[5],buf[6],buf[7]);
    *(float4*)(p+8) = make_float4(buf[8],buf[9],buf[10],buf[11]);
  } else {
    const int vb = mt0*16 + rq;
    #pragma unroll
    for (int r = 0; r < 4; ++r)
      #pragma unroll
      for (int j = 0; j < 3; ++j)
        if (j < ni3)
          orow[320 + (vb+r)*5 + i3base + j] = acc[0][j][r];
  }
}

// ---------------- main fused kernel ----------------
__global__ __launch_bounds__(NT) void tp_linear(
    const float* __restrict__ x, const float* __restrict__ y,
    const float* __restrict__ ws, float* __restrict__ out)
{
  __shared__ __align__(16) uint16_t xr[MB*XRP];    // 15616 B raw x bf16 [b][c]
  __shared__ __align__(16) uint16_t xq[MB*XQP];    // 11520 B permuted [b][i1-major]
  __shared__ __align__(16) uint16_t Tsh[179*16];   //  5728 B T[e][b]
  __shared__ __align__(16) float    cgs[616];      //  2464 B
  __shared__ __align__(16) float    ysm[MB*12];    //   768 B
  __shared__ __align__(16) uint32_t metas[180];    //   720 B
  // total ~36.8 KB -> 4 blocks/CU

  const int tid = threadIdx.x;
  const int b0 = blockIdx.x * MB;
  const short* wt = (const short*)((const char*)ws + WT_BYTE_OFF);

  // ---- stage: y, cg, per-e meta, raw x (all global loads issued up front) ----
  if (tid < MB*9){
    int b = tid/9, c = tid - b*9;
    ysm[b*12 + c] = y[(size_t)b0*9 + tid];
  }
  for (int i = tid; i < 615; i += NT) cgs[i] = ws[i];
  for (int e = tid; e < 179; e += NT){
    int p = 0;
    while (p < 14 && e >= P_TSTART[p+1]) ++p;
    const int r = e - P_TSTART[p];
    const int d3 = P_D3[p], d2 = P_D2[p];
    const int i1 = r / d3, j3 = r - (r/d3)*d3;
    const uint32_t cgi = P_CGOFF[p] + (i1*d2)*d3 + j3;
    metas[e] = cgi | (d3<<10) | (d2<<13) | (P_YOFF[p]<<16);
  }
  for (int idx = tid; idx < MB*120; idx += NT){
    int b = idx/120, q = idx - b*120;
    float4 v = ((const float4*)(x + (size_t)(b0+b)*480))[q];
    *(uint2*)&xr[b*XRP + q*4] = make_uint2(pk2(v.x,v.y), pk2(v.z,v.w));
  }
  __syncthreads();

  // ---- permute l1 region: xq[b][i1*64+u] = xr[b][128+u*3+i1], packed pairs ----
  for (int idx = tid; idx < 1536; idx += NT){
    const int b = idx/96, rem = idx - b*96;
    const int i1 = rem >> 5, up = rem & 31;
    const int s0 = b*XRP + 128 + up*6 + i1;
    const uint32_t a = xr[s0], c = xr[s0+3];
    *(uint32_t*)&xq[b*XQP + i1*64 + up*2] = a | (c<<16);
  }
  // ---- permute l2 region: xq[b][192+i1*32+u] = xr[b][320+u*5+i1] ----
  for (int idx = tid; idx < 1280; idx += NT){
    const int b = idx/80, rem = idx - b*80;
    const int i1 = rem >> 4, up = rem & 15;
    const int s0 = b*XRP + 320 + up*10 + i1;
    const uint32_t a = xr[s0], c = xr[s0+5];
    *(uint32_t*)&xq[b*XQP + 192 + i1*32 + up*2] = a | (c<<16);
  }
  // ---- T[e][b] = sum_i2 cg*y, meta-driven, unrolled (formula validated r2-r4) ----
  for (int idx = tid; idx < 179*16; idx += NT){
    const int e = idx >> 4, b = idx & 15;
    const uint32_t m = metas[e];
    const int cgi = m & 1023, d3 = (m>>10)&7, d2 = (m>>13)&7, yo = m>>16;
    const float* cp = cgs + cgi;
    const float* yp = ysm + b*12 + yo;
    float t = cp[0]*yp[0];
    if (d2 > 1){
      t += cp[d3]*yp[1] + cp[2*d3]*yp[2];
      if (d2 > 3) t += cp[3*d3]*yp[3] + cp[4*d3]*yp[4];
    }
    Tsh[e*16 + b] = (uint16_t)f2bf(t);
  }
  __syncthreads();

  // ---- 3 groups, no further barriers ----
  run_group<0>(wt, out, b0, tid, Tsh, xr, xq);
  run_group<1>(wt, out, b0, tid, Tsh, xr, xq);
  run_group<2>(wt, out, b0, tid, Tsh, xr, xq);
}

extern "C" void kernel_launch(void* const* d_in, const int* in_sizes, int n_in,
                              void* d_out, int out_size, void* d_ws, size_t ws_size,
                              hipStream_t stream)
{
  const float* x  = (const float*)d_in[0];
  const float* y  = (const float*)d_in[1];
  const float* W0 = (const float*)d_in[2];
  const float* W1 = (const float*)d_in[3];
  const float* W2 = (const float*)d_in[4];
  float* out = (float*)d_out;
  float* ws  = (float*)d_ws;   // 2460 B cg + bf16 Wt at +2560

  hipLaunchKernelGGL(prep, dim3(255), dim3(NT), 0, stream, W0, W1, W2, ws);
  hipLaunchKernelGGL(tp_linear, dim3(NBLOCKS), dim3(NT), 0, stream, x, y, ws, out);
}